// Round 3
// baseline (1079.838 us; speedup 1.0000x reference)
//
#include <hip/hip_runtime.h>
#include <hip/hip_fp16.h>
#include <cstdint>
#include <cstddef>

typedef _Float16 half_t;
typedef _Float16 half8 __attribute__((ext_vector_type(8)));
typedef float f32x4 __attribute__((ext_vector_type(4)));

#define TAU_F 0.9f
#define S_ROWS 16384
#define DIN 384
#define DLAT 4096
#define DOUT 128
#define ZSTRIDE 8192   // halves: z row r lives in first 4096 halves of p-row slot r

// ---------------- K0a: f32 -> fp16 flat convert (x) ----------------
__launch_bounds__(256)
__global__ void k0_cvt(const float* __restrict__ in, half_t* __restrict__ out, int n) {
    int i = (blockIdx.x * 256 + threadIdx.x) * 8;
    if (i >= n) return;
    f32x4 a = *(const f32x4*)(in + i);
    f32x4 b = *(const f32x4*)(in + i + 4);
    half8 h;
    h[0] = (half_t)a[0]; h[1] = (half_t)a[1]; h[2] = (half_t)a[2]; h[3] = (half_t)a[3];
    h[4] = (half_t)b[0]; h[5] = (half_t)b[1]; h[6] = (half_t)b[2]; h[7] = (half_t)b[3];
    *(half8*)(out + i) = h;
}

// ------------- K0b: transpose + convert: in[R][C] f32 -> out[C][R] fp16 -------------
__launch_bounds__(256)
__global__ void k0_tcvt(const float* __restrict__ in, half_t* __restrict__ out, int R, int C) {
    __shared__ float tile[64][65];
    const int rb = blockIdx.x * 64, cb = blockIdx.y * 64;
    const int t = threadIdx.x;
    const int lc = t & 63, lr0 = t >> 6;   // 4 rows per pass
#pragma unroll
    for (int i = 0; i < 16; ++i) {
        int lr = lr0 + i * 4;
        tile[lr][lc] = in[(size_t)(rb + lr) * C + cb + lc];
    }
    __syncthreads();
#pragma unroll
    for (int i = 0; i < 16; ++i) {
        int oc = lr0 + i * 4;              // local col of input = row of output
        out[(size_t)(cb + oc) * R + rb + lc] = (half_t)tile[lc][oc];
    }
}

// ---------------- K1: z = x @ W_enc + b_enc  (fp16 MFMA, z -> strided fp16 in p-region) ----------------
// tile 128x128, BK=64, 4 waves (2x2), each wave 64x64 (4x4 frags of 16x16x32)
__launch_bounds__(256, 2)
__global__ void k1_gemm1(const half_t* __restrict__ x16,   // [S][384]
                         const half_t* __restrict__ weT,   // [4096][384]  (W_enc^T)
                         const float*  __restrict__ benc,  // [4096]
                         half_t* __restrict__ zbuf)        // [S][ZSTRIDE], data in first 4096
{
    const int bid = blockIdx.x;
    const int m0 = (bid >> 5) * 128;      // 16384/128 = 128 m-blocks
    const int n0 = (bid & 31) * 128;      // 4096/128  = 32 n-blocks
    const int t = threadIdx.x;
    const int w = t >> 6, lane = t & 63;
    const int wr = (w >> 1) * 64, wc = (w & 1) * 64;

    // padded stride 72 halves (144B) -> ~2-way (free) bank aliasing on frag reads
    __shared__ __align__(16) half_t smem[2 * 128 * 72];
    half_t* Asm = smem;
    half_t* Bsm = smem + 128 * 72;

    const int srow = t >> 3;              // 0..31
    const int scol = (t & 7) * 8;         // halves

    f32x4 acc[4][4] = {};

    for (int k0 = 0; k0 < DIN; k0 += 64) {
        __syncthreads();
#pragma unroll
        for (int p = 0; p < 4; ++p) {
            int r = srow + p * 32;
            half8 av = *(const half8*)(x16 + (size_t)(m0 + r) * DIN + k0 + scol);
            *(half8*)(Asm + r * 72 + scol) = av;
            half8 bv = *(const half8*)(weT + (size_t)(n0 + r) * DIN + k0 + scol);
            *(half8*)(Bsm + r * 72 + scol) = bv;
        }
        __syncthreads();
#pragma unroll
        for (int kk = 0; kk < 2; ++kk) {
            half8 af[4], bf[4];
#pragma unroll
            for (int i = 0; i < 4; ++i) {
                af[i] = *(const half8*)(Asm + (wr + i * 16 + (lane & 15)) * 72 + kk * 32 + (lane >> 4) * 8);
                bf[i] = *(const half8*)(Bsm + (wc + i * 16 + (lane & 15)) * 72 + kk * 32 + (lane >> 4) * 8);
            }
#pragma unroll
            for (int i = 0; i < 4; ++i)
#pragma unroll
                for (int j = 0; j < 4; ++j)
                    acc[i][j] = __builtin_amdgcn_mfma_f32_16x16x32_f16(af[i], bf[j], acc[i][j], 0, 0, 0);
        }
    }

    // epilogue: +b_enc, cvt fp16, LDS bounce for coalesced strided z stores
    __syncthreads();
    half_t* Osm = smem;                   // reuse as [128][128]
#pragma unroll
    for (int i = 0; i < 4; ++i)
#pragma unroll
        for (int j = 0; j < 4; ++j) {
            int col = wc + j * 16 + (lane & 15);
            float bd = benc[n0 + col];
#pragma unroll
            for (int r = 0; r < 4; ++r) {
                int row = wr + i * 16 + (lane >> 4) * 4 + r;
                Osm[row * 128 + col] = (half_t)(acc[i][j][r] + bd);
            }
        }
    __syncthreads();
    // store all 128x128 halves: 8 passes x 256 threads x half8;
    // 16 consecutive lanes cover one contiguous 256B row segment (coalesced)
#pragma unroll
    for (int q = 0; q < 8; ++q) {
        int idx = q * 256 + t;            // 0..2047
        int row = idx >> 4;               // 0..127
        int col = (idx & 15) * 8;         // 0..120
        half8 v = *(const half8*)(Osm + row * 128 + col);
        *(half8*)(zbuf + (size_t)(m0 + row) * ZSTRIDE + n0 + col) = v;
    }
}

// ---------------- K2: per-row softmax + adaptive-top-k threshold + p/latents outputs ----------------
// one block (256 thr) per row; 16 elems/thread (two 8-chunks) in registers;
// 3-round 256-bin radix select on z (softmax is monotone in z -> mask == z >= vthr)
__launch_bounds__(256)
__global__ void k2_softsel(const half_t* __restrict__ zbuf,  // [S][ZSTRIDE]
                           float* __restrict__ p_out,        // [S][4096] (same memory as zbuf!)
                           float* __restrict__ lat_out)      // [S][4096]
{
    const int row = blockIdx.x;
    const int t = threadIdx.x;
    __shared__ float hist[256];
    __shared__ float suf[256];
    __shared__ float red[8];
    __shared__ int bstar;

    const half_t* zr = zbuf + (size_t)row * ZSTRIDE;
    half8 h0 = *(const half8*)(zr + t * 8);
    half8 h1 = *(const half8*)(zr + 2048 + t * 8);
    float zf[16];
#pragma unroll
    for (int i = 0; i < 8; ++i) { zf[i] = (float)h0[i]; zf[8 + i] = (float)h1[i]; }

    // row max
    float m = zf[0];
#pragma unroll
    for (int i = 1; i < 16; ++i) m = fmaxf(m, zf[i]);
#pragma unroll
    for (int off = 32; off > 0; off >>= 1) m = fmaxf(m, __shfl_xor(m, off));
    if ((t & 63) == 0) red[t >> 6] = m;
    __syncthreads();
    m = fmaxf(fmaxf(red[0], red[1]), fmaxf(red[2], red[3]));

    // exp + sum
    float e[16];
    float s = 0.f;
#pragma unroll
    for (int i = 0; i < 16; ++i) { e[i] = __expf(zf[i] - m); s += e[i]; }
#pragma unroll
    for (int off = 32; off > 0; off >>= 1) s += __shfl_xor(s, off);
    __syncthreads();
    if ((t & 63) == 0) red[4 + (t >> 6)] = s;
    __syncthreads();
    const float Sigma = (red[4] + red[5]) + (red[6] + red[7]);
    const float T = TAU_F * Sigma;

    // radix select: find largest value v with suffix-exp-sum >= T; 3 rounds -> bin width ~1.1e-6.
    // Mask boundary sits at z ~ -0.41 (analytic: sigma^2 - 1.2816*sigma, sigma ~ 0.577), where
    // relu zeroes everything -> +-1-element mask jitter cannot change latents/recon;
    // p_softmax doesn't depend on the mask at all.
    float lo = m - 18.0f;
    float wdt = 18.0625f / 256.0f;
    float A = 0.f;
    unsigned active = 0xFFFFu;

    for (int r = 0; r < 3; ++r) {
        hist[t] = 0.f;
        __syncthreads();
        const float invw = 1.0f / wdt;
        int bins[16];
#pragma unroll
        for (int i = 0; i < 16; ++i) {
            int b = -1;
            if (active & (1u << i)) {
                b = (int)floorf((zf[i] - lo) * invw);
                b = b < 0 ? 0 : (b > 255 ? 255 : b);
                atomicAdd(&hist[b], e[i]);
            }
            bins[i] = b;
        }
        __syncthreads();
        suf[t] = hist[t];
        __syncthreads();
#pragma unroll
        for (int d = 1; d < 256; d <<= 1) {
            float v = (t + d < 256) ? suf[t + d] : 0.f;
            __syncthreads();
            suf[t] += v;
            __syncthreads();
        }
        if (t == 0) bstar = 0;
        __syncthreads();
        if (A + suf[t] >= T) atomicMax(&bstar, t);
        __syncthreads();
        const int bs = bstar;
        A += (bs < 255) ? suf[bs + 1] : 0.f;
        lo += bs * wdt;
        wdt *= (1.0f / 256.0f);
        unsigned na = 0;
#pragma unroll
        for (int i = 0; i < 16; ++i) if (bins[i] == bs) na |= (1u << i);
        active = na;
        __syncthreads();
    }

    const float vthr = lo;                // lower edge of final ~1e-6-wide bin
    const float invS = 1.0f / Sigma;

    // stores: two 8-elem chunks per thread -> 32B/lane contiguous per wave
    float* pr = p_out + (size_t)row * DLAT;   // overwrites this row's z slot (only we read it)
    float* lr = lat_out + (size_t)row * DLAT;
#pragma unroll
    for (int c = 0; c < 2; ++c) {
        int base = c * 2048 + t * 8;
        f32x4 pv0, pv1, lv0, lv1;
#pragma unroll
        for (int j = 0; j < 4; ++j) {
            int i = c * 8 + j;
            pv0[j] = e[i] * invS;
            lv0[j] = (zf[i] > 0.f && zf[i] >= vthr) ? zf[i] : 0.f;
            pv1[j] = e[i + 4] * invS;
            lv1[j] = (zf[i + 4] > 0.f && zf[i + 4] >= vthr) ? zf[i + 4] : 0.f;
        }
        *(f32x4*)(pr + base) = pv0;
        *(f32x4*)(pr + base + 4) = pv1;
        *(f32x4*)(lr + base) = lv0;
        *(f32x4*)(lr + base + 4) = lv1;
    }
}

// ---------------- K3: recon = tanh(latents @ W_dec + b_dec) ----------------
// reads masked f32 latents from d_out, converts to fp16 during A-staging.
// tile 64x128, BK=64, 4 waves (2x2), each wave 32x64 (2x4 frags)
__launch_bounds__(256, 2)
__global__ void k3_gemm2(const float* __restrict__ lat,    // [S][4096]
                         const half_t* __restrict__ wdT,   // [128][4096] (W_dec^T)
                         const float* __restrict__ bdec,   // [128]
                         float* __restrict__ recon)        // [S][128]
{
    const int m0 = blockIdx.x * 64;
    const int t = threadIdx.x;
    const int w = t >> 6, lane = t & 63;
    const int wr = (w >> 1) * 32, wc = (w & 1) * 64;

    __shared__ __align__(16) half_t smem[(64 + 128) * 72];
    half_t* Asm = smem;                 // [64][72]
    half_t* Bsm = smem + 64 * 72;       // [128][72]

    const int srow = t >> 3;            // 0..31
    const int scol = (t & 7) * 8;

    f32x4 acc[2][4] = {};

    for (int k0 = 0; k0 < DLAT; k0 += 64) {
        __syncthreads();
#pragma unroll
        for (int p = 0; p < 2; ++p) {
            int r = srow + p * 32;
            const float* src = lat + (size_t)(m0 + r) * DLAT + k0 + scol;
            f32x4 a0 = *(const f32x4*)src;
            f32x4 a1 = *(const f32x4*)(src + 4);
            half8 hv;
#pragma unroll
            for (int i = 0; i < 4; ++i) { hv[i] = (half_t)a0[i]; hv[4 + i] = (half_t)a1[i]; }
            *(half8*)(Asm + r * 72 + scol) = hv;
        }
#pragma unroll
        for (int p = 0; p < 4; ++p) {
            int r = srow + p * 32;      // 0..127
            half8 bv = *(const half8*)(wdT + (size_t)r * DLAT + k0 + scol);
            *(half8*)(Bsm + r * 72 + scol) = bv;
        }
        __syncthreads();
#pragma unroll
        for (int kk = 0; kk < 2; ++kk) {
            half8 af[2], bf[4];
#pragma unroll
            for (int i = 0; i < 2; ++i)
                af[i] = *(const half8*)(Asm + (wr + i * 16 + (lane & 15)) * 72 + kk * 32 + (lane >> 4) * 8);
#pragma unroll
            for (int j = 0; j < 4; ++j)
                bf[j] = *(const half8*)(Bsm + (wc + j * 16 + (lane & 15)) * 72 + kk * 32 + (lane >> 4) * 8);
#pragma unroll
            for (int i = 0; i < 2; ++i)
#pragma unroll
                for (int j = 0; j < 4; ++j)
                    acc[i][j] = __builtin_amdgcn_mfma_f32_16x16x32_f16(af[i], bf[j], acc[i][j], 0, 0, 0);
        }
    }

#pragma unroll
    for (int i = 0; i < 2; ++i)
#pragma unroll
        for (int j = 0; j < 4; ++j) {
            int col = wc + j * 16 + (lane & 15);
            float bd = bdec[col];
#pragma unroll
            for (int r = 0; r < 4; ++r) {
                int row = m0 + wr + i * 16 + (lane >> 4) * 4 + r;
                recon[(size_t)row * DOUT + col] = tanhf(acc[i][j][r] + bd);
            }
        }
}

// ---------------- launch ----------------
extern "C" void kernel_launch(void* const* d_in, const int* in_sizes, int n_in,
                              void* d_out, int out_size, void* d_ws, size_t ws_size,
                              hipStream_t stream) {
    (void)in_sizes; (void)n_in; (void)out_size; (void)ws_size;
    const float* x    = (const float*)d_in[0];
    const float* Wenc = (const float*)d_in[1];
    const float* benc = (const float*)d_in[2];
    const float* Wdec = (const float*)d_in[3];
    const float* bdec = (const float*)d_in[4];

    float* recon = (float*)d_out;                        // [16384][128]
    float* p_out = (float*)d_out + 2097152;              // [16384][4096]
    float* l_out = (float*)d_out + 69206016;             // [16384][4096]
    half_t* zbuf = (half_t*)p_out;                       // z16 interleaved in p slots

    char* ws = (char*)d_ws;                              // 16 MB total
    half_t* x16 = (half_t*)(ws);                         // 12,582,912 B
    half_t* weT = (half_t*)(ws + 12582912);              //  3,145,728 B
    half_t* wdT = (half_t*)(ws + 15728640);              //  1,048,576 B

    hipLaunchKernelGGL(k0_cvt,  dim3(3072),   dim3(256), 0, stream, x, x16, S_ROWS * DIN);
    hipLaunchKernelGGL(k0_tcvt, dim3(6, 64),  dim3(256), 0, stream, Wenc, weT, DIN, DLAT);
    hipLaunchKernelGGL(k0_tcvt, dim3(64, 2),  dim3(256), 0, stream, Wdec, wdT, DLAT, DOUT);
    hipLaunchKernelGGL(k1_gemm1, dim3(4096),  dim3(256), 0, stream, x16, weT, benc, zbuf);
    hipLaunchKernelGGL(k2_softsel, dim3(16384), dim3(256), 0, stream, zbuf, p_out, l_out);
    hipLaunchKernelGGL(k3_gemm2, dim3(256),   dim3(256), 0, stream, l_out, wdT, bdec, recon);
}